// Round 10
// baseline (295.350 us; speedup 1.0000x reference)
//
#include <hip/hip_runtime.h>
#include <hip/hip_bf16.h>

// Problem constants
constexpr int DIMD  = 1152;
constexpr int NHD   = 12;     // query heads
constexpr int KVHD  = 2;      // kv heads
constexpr int HDD   = 96;     // head dim
constexpr int GRPS  = 6;      // GQA group size
constexpr int SEQL  = 2048;
constexpr int BSZ4  = 4;
constexpr int MROWS = BSZ4 * SEQL;           // 8192
constexpr int NQKV  = DIMD + 2 * KVHD * HDD; // 1536
constexpr float SCALE = 0.10206207261596577f; // 96^-0.5
// exp2-domain scale: SCALE * log2(e). v_exp_f32 computes 2^x natively.
constexpr float SCALE2 = 0.10206207261596577f * 1.4426950408889634f;

typedef short  bf16x8 __attribute__((ext_vector_type(8)));
typedef float  f32x4  __attribute__((ext_vector_type(4)));
typedef float  f32x16 __attribute__((ext_vector_type(16)));
typedef unsigned int u32x4_t __attribute__((ext_vector_type(4)));

typedef __attribute__((address_space(3))) unsigned int       lds_u32_t;
typedef __attribute__((address_space(1))) const unsigned int glb_u32_t;

__device__ __forceinline__ void gload16(const unsigned short* g, unsigned short* l) {
    // async global->LDS DMA, 16B/lane; LDS dest = wave-uniform base + lane*16
    __builtin_amdgcn_global_load_lds((glb_u32_t*)(const void*)g,
                                     (lds_u32_t*)(void*)l, 16, 0, 0);
}

__device__ __forceinline__ unsigned short f2bf(float f) {
    unsigned int u = __builtin_bit_cast(unsigned int, f);
    u += 0x7fff + ((u >> 16) & 1);   // RNE
    return (unsigned short)(u >> 16);
}

__device__ __forceinline__ unsigned cvtpk(float a, float b) {
    // packed f32->bf16 (RNE): lo16 = bf16(a), hi16 = bf16(b)
    unsigned r;
    asm volatile("v_cvt_pk_bf16_f32 %0, %1, %2" : "=v"(r) : "v"(a), "v"(b));
    return r;
}

__device__ __forceinline__ float ex2(float x) {
    // raw v_exp_f32: D = 2^S0 (glibc macro-clash-free replacement for __exp2f)
    float r;
    asm volatile("v_exp_f32 %0, %1" : "=v"(r) : "v"(x));
    return r;
}

// ---------------------------------------------------------------------------
// prep: fused fp32->bf16 converts (x, qw, kvw, wow) + RoPE cos/sin table.
// ---------------------------------------------------------------------------
__device__ __forceinline__ void cvt4(const float4* __restrict__ s,
                                     ushort4* __restrict__ d, int i) {
    float4 f = s[i];
    ushort4 o;
    o.x = f2bf(f.x); o.y = f2bf(f.y); o.z = f2bf(f.z); o.w = f2bf(f.w);
    d[i] = o;
}

__global__ __launch_bounds__(256) void prep_kernel(
    const float4* __restrict__ x,   const float4* __restrict__ qw,
    const float4* __restrict__ kvw, const float4* __restrict__ wow,
    ushort4* __restrict__ xb,   ushort4* __restrict__ qwb,
    ushort4* __restrict__ kvwb, ushort4* __restrict__ wowb,
    const int* __restrict__ sp, float2* __restrict__ tab)
{
    constexpr int X4  = MROWS * DIMD / 4;
    constexpr int W4  = DIMD * DIMD / 4;
    constexpr int KV4 = 2 * KVHD * HDD * DIMD / 4;
    constexpr int NT  = SEQL * 48;
    int i = blockIdx.x * 256 + threadIdx.x;
    if (i < X4)  { cvt4(x, xb, i); return; }
    i -= X4;
    if (i < W4)  { cvt4(qw, qwb, i); return; }
    i -= W4;
    if (i < KV4) { cvt4(kvw, kvwb, i); return; }
    i -= KV4;
    if (i < W4)  { cvt4(wow, wowb, i); return; }
    i -= W4;
    if (i < NT) {
        int s = i / 48, j = i - (i / 48) * 48;
        float th = powf(10000.0f, -(float)(2 * j) / 96.0f);
        float ang = (float)(s + *sp) * th;
        float sn, cs; sincosf(ang, &sn, &cs);
        tab[i] = make_float2(cs, sn);
    }
}

// ---------------------------------------------------------------------------
// Kernel 1: QKV projection, Round 10: 128x64 tiles -> 1536 blocks (6 WG/CU,
// was 768 = 3/CU with zero backfill; R1 occupancy was 17% vs 37.5% cap —
// grid starvation, the same failure mode as R3's attn). Dbuf + counted
// vmcnt(3) (3 gload16/wave/tile). LDS 24 KB. XCD swizzle (192-chunk).
// ---------------------------------------------------------------------------
__global__ __launch_bounds__(256, 5) void qkv_mfma_kernel(
    const unsigned short* __restrict__ xb,  const unsigned short* __restrict__ qwb,
    const unsigned short* __restrict__ kvwb,
    const float* __restrict__ qb,  const float* __restrict__ kvb,
    const float2* __restrict__ tab,
    unsigned short* __restrict__ Qo, unsigned short* __restrict__ Ko,
    unsigned short* __restrict__ VTo)
{
    __shared__ __align__(16) unsigned short As[2][128 * 32];  // 16 KB
    __shared__ __align__(16) unsigned short Bs[2][64 * 32];   //  8 KB

    const int tid  = threadIdx.x;
    const int w    = tid >> 6;
    const int lane = tid & 63;
    const int l16  = lane & 15;
    const int quad = lane >> 4;
    const int wm   = w >> 1, wn = w & 1;

    // XCD-aware swizzle: 1536 blocks -> 192 contiguous per XCD
    const int flat = (int)(blockIdx.y * gridDim.x + blockIdx.x);  // 0..1535
    const int swz  = (flat & 7) * 192 + (flat >> 3);
    const int m0   = (swz / 24) * 128;
    const int n0   = (swz % 24) * 64;

    const unsigned short* Abase = xb + (size_t)m0 * DIMD;
    const unsigned short* Bbase = (n0 < DIMD)
        ? qwb  + (size_t)n0 * DIMD
        : kvwb + (size_t)(n0 - DIMD) * DIMD;

    const int srow = w * 16 + (lane >> 2);
    const int scol = (lane & 3) * 8;

    f32x4 acc[4][2];
    #pragma unroll
    for (int mi = 0; mi < 4; mi++)
        #pragma unroll
        for (int ni = 0; ni < 2; ni++) acc[mi][ni] = (f32x4){0.f, 0.f, 0.f, 0.f};

    constexpr int NK = DIMD / 32;   // 36

    // prologue: stage tile 0 (per wave: 2 A + 1 B = 3 loads)
    gload16(Abase + (size_t)srow        * DIMD + scol, &As[0][w * 512]);
    gload16(Abase + (size_t)(srow + 64) * DIMD + scol, &As[0][2048 + w * 512]);
    gload16(Bbase + (size_t)srow        * DIMD + scol, &Bs[0][w * 512]);

    for (int kt = 0; kt < NK; kt++) {
        const int cur = kt & 1;
        if (kt + 1 < NK) {
            const int k0 = (kt + 1) * 32;
            gload16(Abase + (size_t)srow        * DIMD + k0 + scol, &As[cur ^ 1][w * 512]);
            gload16(Abase + (size_t)(srow + 64) * DIMD + k0 + scol, &As[cur ^ 1][2048 + w * 512]);
            gload16(Bbase + (size_t)srow        * DIMD + k0 + scol, &Bs[cur ^ 1][w * 512]);
            asm volatile("s_waitcnt vmcnt(3)" ::: "memory");  // tile kt done; kt+1 in flight
        } else {
            asm volatile("s_waitcnt vmcnt(0)" ::: "memory");
        }
        __builtin_amdgcn_s_barrier();
        asm volatile("" ::: "memory");

        bf16x8 af[4], bfr[2];
        #pragma unroll
        for (int mi = 0; mi < 4; mi++)
            af[mi] = *(const bf16x8*)&As[cur][(wm * 64 + mi * 16 + l16) * 32 + quad * 8];
        #pragma unroll
        for (int ni = 0; ni < 2; ni++)
            bfr[ni] = *(const bf16x8*)&Bs[cur][(wn * 32 + ni * 16 + l16) * 32 + quad * 8];
        #pragma unroll
        for (int mi = 0; mi < 4; mi++)
            #pragma unroll
            for (int ni = 0; ni < 2; ni++)
                acc[mi][ni] = __builtin_amdgcn_mfma_f32_16x16x32_bf16(
                    af[mi], bfr[ni], acc[mi][ni], 0, 0, 0);

        asm volatile("" ::: "memory");
        __builtin_amdgcn_s_barrier();
    }

    #pragma unroll
    for (int ni = 0; ni < 2; ni++) {
        const int n   = n0 + wn * 32 + ni * 16 + l16;
        const bool isQ = (n < DIMD);
        const int jj  = n - DIMD;
        const bool isK = !isQ && (jj < KVHD * HDD);
        const int d   = isQ ? (n % HDD) : (jj % HDD);
        const int hh  = isQ ? (n / HDD) : ((jj / HDD) & 1);
        const float bias = isQ ? qb[n] : kvb[jj];
        const bool doRope = isQ || isK;
        const int de2 = (d >> 1);
        const float sg = (n & 1) ? 1.0f : -1.0f;
        #pragma unroll
        for (int mi = 0; mi < 4; mi++) {
            #pragma unroll
            for (int r = 0; r < 4; r++) {
                const int m = m0 + wm * 64 + mi * 16 + quad * 4 + r;
                const int b = m >> 11;
                const int s = m & (SEQL - 1);
                float v  = acc[mi][ni][r] + bias;
                float pv = __shfl_xor(v, 1, 64);
                float o = v;
                if (doRope) {
                    float2 cs2 = tab[s * 48 + de2];
                    o = v * cs2.x + sg * pv * cs2.y;
                }
                if (isQ)
                    Qo[(((size_t)b * NHD + hh) * SEQL + s) * HDD + d] = f2bf(o);
                else if (isK)
                    Ko[(((size_t)b * KVHD + hh) * SEQL + s) * HDD + d] = f2bf(o);
                else
                    VTo[(((size_t)b * KVHD + hh) * HDD + d) * SEQL + s] = f2bf(o);
            }
        }
    }
}

// ---------------------------------------------------------------------------
// Kernel 2: bf16 MFMA causal flash attention — R9 kernel VERBATIM (measured
// 83.8 µs, zero bank conflicts). Attn is barrier/latency-structure-bound:
// three rounds of pipe-level fixes (FETCH -3x, VALU cuts, conflicts -100%)
// each landed as predicted on their counter and moved dur < 1%.
// ---------------------------------------------------------------------------
__global__ __launch_bounds__(256, 3) void attn_mfma_kernel(
    const unsigned short* __restrict__ Q, const unsigned short* __restrict__ K,
    const unsigned short* __restrict__ VT, unsigned short* __restrict__ AO)
{
    constexpr int KHALF = 64 * 104;                      // shorts per K buffer
    __shared__ __align__(16) unsigned short Ks[2 * KHALF]; // 26624 B (dbuf)
    __shared__ __align__(16) unsigned short VTs[96 * 72];  // 13824 B
    __shared__ float Al[4][32];                            // 512 B (tot 40960)

    const int tid  = threadIdx.x;
    const int w    = tid >> 6;
    const int lane = tid & 63;
    const int l31  = lane & 31;
    const int hi   = lane >> 5;
    const int qh   = w >> 1;      // q-half of the 64-row block
    const int th   = w & 1;       // t-half of each 64-t tile
    const int th32 = th * 32;

    // XCD KV-affinity + per-XCD LPT
    const int idx  = (int)blockIdx.x;
    const int grp  = idx & 7;            // -> XCD (round-robin dispatch)
    const int j0   = idx >> 3;           // 0..191, qt-descending
    const int jq   = j0 / 6;
    const int hrem = j0 - jq * 6;
    const int qt   = 31 - jq;
    const int b    = grp >> 1;
    const int kvh  = grp & 1;
    const int h    = kvh * GRPS + hrem;
    const int nkb  = qt + 1;

    const unsigned short* Qbase  = Q  + (((size_t)b * NHD  + h)   * SEQL) * HDD;
    const unsigned short* Kbase  = K  + (((size_t)b * KVHD + kvh) * SEQL) * HDD;
    const unsigned short* VTbase = VT + (((size_t)b * KVHD + kvh) * HDD)  * SEQL;

    // --- staging maps (identical to R6/R8): instr i = w + 4*j
    int goff[7]; int gkind[7]; int loff[7];
    #pragma unroll
    for (int jj = 0; jj < 7; jj++) {
        const int i = w + 4 * jj;
        gkind[jj] = 2; goff[jj] = 0; loff[jj] = 0;
        if (i < 13) {
            int slot = i * 64 + lane;
            int r = slot / 13, g = slot - r * 13;
            goff[jj]  = r * HDD + (g < 12 ? g * 8 : 0);
            gkind[jj] = 0;
            loff[jj]  = i * 512;
        } else if (i < 27) {
            int iv = i - 13;
            int slot = iv * 64 + lane;
            if (slot < 864) {
                int r = slot / 9, g = slot - r * 9;
                goff[jj]  = r * SEQL + (g < 8 ? g * 8 : 0);
                gkind[jj] = 1;
                loff[jj]  = iv * 512;
            }
        }
    }

    // --- Q fragments (B-operand, 32x32x16): lane l31 = q-col, k = hi*8 + j
    const int qv = qt * 64 + qh * 32;    // wave's q base
    bf16x8 qf[6];
    {
        const unsigned short* qp = Qbase + (size_t)(qv + l31) * HDD + hi * 8;
        #pragma unroll
        for (int ks = 0; ks < 6; ks++) qf[ks] = *(const bf16x8*)(qp + ks * 16);
    }

    float m_r = -1e30f, l_r = 0.0f;
    f32x16 oacc[3];
    #pragma unroll
    for (int nn = 0; nn < 3; nn++)
        #pragma unroll
        for (int r = 0; r < 16; r++) oacc[nn][r] = 0.0f;

    // --- prologue: issue K0 -> buf0, then V0 (K before V: wait math relies on it)
    #pragma unroll
    for (int jj = 0; jj < 7; jj++)
        if (gkind[jj] == 0)
            gload16(Kbase + goff[jj], &Ks[loff[jj]]);
    #pragma unroll
    for (int jj = 0; jj < 7; jj++)
        if (gkind[jj] == 1) {
            if ((w + 4 * jj) < 26 || lane < 32)
                gload16(VTbase + goff[jj], &VTs[loff[jj]]);
        }

    for (int kb = 0; kb < nkb; kb++) {
        const int  cur  = kb & 1;
        const bool more = (kb + 1 < nkb);
        const int  k0   = kb * 64;
        const bool active = (k0 + th32 <= qv + 31);   // wave-uniform

        // ---- issue K(kb+1) into the other buffer, then wait for K(kb) only.
        if (more) {
            const size_t kg = (size_t)(kb + 1) * 64 * HDD;
            #pragma unroll
            for (int jj = 0; jj < 7; jj++)
                if (gkind[jj] == 0)
                    gload16(Kbase + kg + goff[jj], &Ks[(cur ^ 1) * KHALF + loff[jj]]);
            asm volatile("s_waitcnt vmcnt(6)" ::: "memory");
        } else {
            asm volatile("s_waitcnt vmcnt(3)" ::: "memory");
        }
        __builtin_amdgcn_s_barrier();
        asm volatile("" ::: "memory");

        bf16x8 pa[2];
        bool resc = false;

        if (active) {
            // ---- S^T = K[t-half] * Q^T : C col l31 = q, row regs = t_local
            const unsigned short* ksb = &Ks[cur * KHALF + th32 * 104];
            f32x16 s;
            #pragma unroll
            for (int r = 0; r < 16; r++) s[r] = 0.0f;
            __builtin_amdgcn_s_setprio(1);
            #pragma unroll
            for (int ks = 0; ks < 6; ks++) {
                bf16x8 kf = *(const bf16x8*)&ksb[l31 * 104 + ks * 16 + hi * 8];
                s = __builtin_amdgcn_mfma_f32_32x32x16_bf16(kf, qf[ks], s, 0, 0, 0);
            }
            __builtin_amdgcn_s_setprio(0);

            // ---- online softmax (exp2 domain); lane q = qv + l31
            const int qabs = qv + l31;
            float p[16];
            float mx = -3e30f;
            const bool domask = (k0 + th32 + 31 > qv);
            #pragma unroll
            for (int r = 0; r < 16; r++) {
                const int tl = (r & 3) + 8 * (r >> 2) + 4 * hi;
                float x = s[r] * SCALE2;
                if (domask && (k0 + th32 + tl > qabs)) x = -1e30f;
                p[r] = x;
                mx = fmaxf(mx, x);
            }
            mx = fmaxf(mx, __shfl_xor(mx, 32, 64));

            // defer-max: skip rescale when max didn't grow past THR=8
            resc = !__all(mx <= m_r + 8.0f);
            float mnew = m_r, al = 1.0f;
            if (resc) {
                mnew = fmaxf(m_r, mx);
                al = ex2(m_r - mnew);
                if (hi == 0) Al[w][l31] = al;
            }
            float sum = 0.0f;
            #pragma unroll
            for (int r = 0; r < 16; r++) {
                p[r] = ex2(p[r] - mnew);
                sum += p[r];
            }
            sum += __shfl_xor(sum, 32, 64);
            l_r = l_r * al + sum;
            m_r = mnew;

            // ---- P -> two bf16 A-frags in-register (one u32-pair swap per tk)
            #pragma unroll
            for (int tk = 0; tk < 2; tk++) {
                const int base = tk * 8;
                unsigned pkA0 = cvtpk(p[base + 0], p[base + 1]);
                unsigned pkA1 = cvtpk(p[base + 2], p[base + 3]);
                unsigned pkB0 = cvtpk(p[base + 4], p[base + 5]);
                unsigned pkB1 = cvtpk(p[base + 6], p[base + 7]);
                unsigned S0 = hi ? pkA0 : pkB0;
                unsigned S1 = hi ? pkA1 : pkB1;
                unsigned R0 = __shfl_xor(S0, 32, 64);
                unsigned R1 = __shfl_xor(S1, 32, 64);
                u32x4_t wv;
                wv[0] = hi ? R0 : pkA0;
                wv[1] = hi ? R1 : pkA1;
                wv[2] = hi ? pkB0 : R0;
                wv[3] = hi ? pkB1 : R1;
                pa[tk] = __builtin_bit_cast(bf16x8, wv);
            }
        }

        // ---- wait for V(kb): outstanding = V(kb), K(kb+1); min K' = 3
        if (more) asm volatile("s_waitcnt vmcnt(3)" ::: "memory");
        else      asm volatile("s_waitcnt vmcnt(0)" ::: "memory");
        __builtin_amdgcn_s_barrier();
        asm volatile("" ::: "memory");

        if (active) {
            // ---- rescale O only when max moved (wave-uniform branch)
            if (resc) {
                const float4 a0 = *(const float4*)&Al[w][hi * 4];
                const float4 a1 = *(const float4*)&Al[w][8 + hi * 4];
                const float4 a2 = *(const float4*)&Al[w][16 + hi * 4];
                const float4 a3 = *(const float4*)&Al[w][24 + hi * 4];
                const float ab[16] = {a0.x, a0.y, a0.z, a0.w,
                                      a1.x, a1.y, a1.z, a1.w,
                                      a2.x, a2.y, a2.z, a2.w,
                                      a3.x, a3.y, a3.z, a3.w};
                #pragma unroll
                for (int nn = 0; nn < 3; nn++)
                    #pragma unroll
                    for (int r = 0; r < 16; r++) oacc[nn][r] *= ab[r];
            }

            // ---- O += P V[t-half]  (C: col l31 = d, row regs = q_local)
            __builtin_amdgcn_s_setprio(1);
            #pragma unroll
            for (int nn = 0; nn < 3; nn++) {
                const unsigned short* vr = &VTs[(nn * 32 + l31) * 72 + th32 + hi * 8];
                bf16x8 vb0 = *(const bf16x8*)(vr);
                bf16x8 vb1 = *(const bf16x8*)(vr + 16);
                f32x16 a = oacc[nn];
                a = __builtin_amdgcn_mfma_f32_32x32x16_bf16(pa[0], vb0, a, 0, 0, 0);
                a = __builtin_amdgcn_mfma_f32_32x32x16_bf16(pa[1], vb1, a, 0, 0, 0);
                oacc[nn] = a;
            }
            __builtin_amdgcn_s_setprio(0);
        }

        // ---- all waves done reading VTs -> safe to overwrite with V(kb+1)
        asm volatile("" ::: "memory");
        __builtin_amdgcn_s_barrier();
        asm volatile("" ::: "memory");

        if (more) {
            const int kg = (kb + 1) * 64;
            #pragma unroll
            for (int jj = 0; jj < 7; jj++)
                if (gkind[jj] == 1) {
                    if ((w + 4 * jj) < 26 || lane < 32)
                        gload16(VTbase + kg + goff[jj], &VTs[loff[jj]]);
                }
        }
    }

    // ---- epilogue: merge the two t-half states per q-pair, normalize, store.
    __syncthreads();
    float* Mx  = (float*)VTs;          // [4][32] running max
    float* Lx  = Mx + 128;             // [4][32] running sum
    float* Gs  = Lx + 128;             // [4][32] merge factor
    float* Osc = (float*)Ks;           // [2][32][96] partner O dump
    if (hi == 0) { Mx[w * 32 + l31] = m_r; Lx[w * 32 + l31] = l_r; }
    __syncthreads();
    {
        const int wp = w ^ 1;          // t-half partner (same q-half)
        const float m_p = Mx[wp * 32 + l31];
        const float l_p = Lx[wp * 32 + l31];
        const float mm  = fmaxf(m_r, m_p);
        const float fs  = ex2(m_r - mm);
        const float lt  = l_r * fs + l_p * ex2(m_p - mm);
        if (hi == 0) Gs[w * 32 + l31] = fs / lt;   // folds 1/l normalization
    }
    __syncthreads();
    float gr[16];
    {
        const float4 a0 = *(const float4*)&Gs[w * 32 + hi * 4];
        const float4 a1 = *(const float4*)&Gs[w * 32 + 8 + hi * 4];
        const float4 a2 = *(const float4*)&Gs[w * 32 + 16 + hi * 4];
        const float4 a3 = *(const float4*)&Gs[w * 32 + 24 + hi * 4];
        gr[0]  = a0.x; gr[1]  = a0.y; gr[2]  = a0.z; gr[3]  = a0.w;
        gr[4]  = a1.x; gr[5]  = a1.y; gr[6]  = a1.z; gr[7]  = a1.w;
        gr[8]  = a2.x; gr[9]  = a2.y; gr[10] = a2.z; gr[11] = a2.w;
        gr[12] = a3.x; gr[13] = a3.y; gr[14] = a3.z; gr[15] = a3.w;
    }
    #pragma unroll
    for (int nn = 0; nn < 3; nn++)
        #pragma unroll
        for (int r = 0; r < 16; r++) oacc[nn][r] *= gr[r];

    if (th == 1) {
        #pragma unroll
        for (int nn = 0; nn < 3; nn++)
            #pragma unroll
            for (int r = 0; r < 16; r++) {
                const int ql = (r & 3) + 8 * (r >> 2) + 4 * hi;
                Osc[(qh * 32 + ql) * 96 + nn * 32 + l31] = oacc[nn][r];
            }
    }
    __syncthreads();
    if (th == 0) {
        #pragma unroll
        for (int nn = 0; nn < 3; nn++)
            #pragma unroll
            for (int r = 0; r < 16; r++) {
                const int ql = (r & 3) + 8 * (r >> 2) + 4 * hi;
                const float v2 = oacc[nn][r]
                               + Osc[(qh * 32 + ql) * 96 + nn * 32 + l31];
                AO[((size_t)b * SEQL + qv + ql) * DIMD + h * HDD + nn * 32 + l31]
                    = f2bf(v2);
            }
    }
}

// ---------------------------------------------------------------------------
// Kernel 3: output projection, 128x64 tiles -> 1152 blocks (4.5 WG/CU, was
// 576 = 2.25/CU). Same dbuf + vmcnt(3) pipeline. XCD swizzle (144-chunk).
// ---------------------------------------------------------------------------
__global__ __launch_bounds__(256, 5) void out_mfma_kernel(
    const unsigned short* __restrict__ Ab, const unsigned short* __restrict__ Wb,
    const float* __restrict__ wob, float* __restrict__ out)
{
    __shared__ __align__(16) unsigned short As[2][128 * 32];  // 16 KB
    __shared__ __align__(16) unsigned short Bs[2][64 * 32];   //  8 KB

    const int tid  = threadIdx.x;
    const int w    = tid >> 6;
    const int lane = tid & 63;
    const int l16  = lane & 15;
    const int quad = lane >> 4;
    const int wm   = w >> 1, wn = w & 1;

    const int flat = (int)(blockIdx.y * gridDim.x + blockIdx.x);  // 0..1151
    const int swz  = (flat & 7) * 144 + (flat >> 3);
    const int m0   = (swz / 18) * 128;
    const int n0   = (swz % 18) * 64;

    const unsigned short* Abase = Ab + (size_t)m0 * DIMD;
    const unsigned short* Bbase = Wb + (size_t)n0 * DIMD;

    const int srow = w * 16 + (lane >> 2);
    const int scol = (lane & 3) * 8;

    f32x4 acc[4][2];
    #pragma unroll
    for (int mi = 0; mi < 4; mi++)
        #pragma unroll
        for (int ni = 0; ni < 2; ni++) acc[mi][ni] = (f32x4){0.f, 0.f, 0.f, 0.f};

    constexpr int NK = DIMD / 32;   // 36

    gload16(Abase + (size_t)srow        * DIMD + scol, &As[0][w * 512]);
    gload16(Abase + (size_t)(srow + 64) * DIMD + scol, &As[0][2048 + w * 512]);
    gload16(Bbase + (size_t)srow        * DIMD + scol, &Bs[0][w * 512]);

    for (int kt = 0; kt < NK; kt++) {
        const int cur = kt & 1;
        if (kt + 1 < NK) {
            const int k0 = (kt + 1) * 32;
            gload16(Abase + (size_t)srow        * DIMD + k0 + scol, &As[cur ^ 1][w * 512]);
            gload16(Abase + (size_t)(srow + 64) * DIMD + k0 + scol, &As[cur ^ 1][2048 + w * 512]);
            gload16(Bbase + (size_t)srow        * DIMD + k0 + scol, &Bs[cur ^ 1][w * 512]);
            asm volatile("s_waitcnt vmcnt(3)" ::: "memory");
        } else {
            asm volatile("s_waitcnt vmcnt(0)" ::: "memory");
        }
        __builtin_amdgcn_s_barrier();
        asm volatile("" ::: "memory");

        bf16x8 af[4], bfr[2];
        #pragma unroll
        for (int mi = 0; mi < 4; mi++)
            af[mi] = *(const bf16x8*)&As[cur][(wm * 64 + mi * 16 + l16) * 32 + quad * 8];
        #pragma unroll
        for (int ni = 0; ni < 2; ni++)
            bfr[ni] = *(const bf16x8*)&Bs[cur][(wn * 32 + ni * 16 + l16) * 32 + quad * 8];
        #pragma unroll
        for (int mi = 0; mi < 4; mi++)
            #pragma unroll
            for (int ni = 0; ni < 2; ni++)
                acc[mi][ni] = __builtin_amdgcn_mfma_f32_16x16x32_bf16(
                    af[mi], bfr[ni], acc[mi][ni], 0, 0, 0);

        asm volatile("" ::: "memory");
        __builtin_amdgcn_s_barrier();
    }

    #pragma unroll
    for (int ni = 0; ni < 2; ni++) {
        const int n = n0 + wn * 32 + ni * 16 + l16;
        const float bias = wob[n];
        #pragma unroll
        for (int mi = 0; mi < 4; mi++) {
            #pragma unroll
            for (int r = 0; r < 4; r++) {
                const int m = m0 + wm * 64 + mi * 16 + quad * 4 + r;
                out[(size_t)m * DIMD + n] = acc[mi][ni][r] + bias;
            }
        }
    }
}

// ---------------------------------------------------------------------------
extern "C" void kernel_launch(void* const* d_in, const int* in_sizes, int n_in,
                              void* d_out, int out_size, void* d_ws, size_t ws_size,
                              hipStream_t stream)
{
    const float* x   = (const float*)d_in[0];
    // d_in[1] = mask: exactly triu(-1e9, k=1) -> causal predicate in-kernel
    const float* qw  = (const float*)d_in[2];
    const float* qb  = (const float*)d_in[3];
    const float* kvw = (const float*)d_in[4];
    const float* kvb = (const float*)d_in[5];
    const float* wow = (const float*)d_in[6];
    const float* wob = (const float*)d_in[7];
    const int*   sp  = (const int*)d_in[8];

    const size_t xN   = (size_t)MROWS * DIMD;
    const size_t qwN  = (size_t)DIMD * DIMD;
    const size_t kvwN = (size_t)2 * KVHD * HDD * DIMD;
    const size_t qN   = (size_t)BSZ4 * NHD  * SEQL * HDD;
    const size_t kvN  = (size_t)BSZ4 * KVHD * SEQL * HDD;

    unsigned short* xb   = (unsigned short*)d_ws;
    unsigned short* qwb  = xb   + xN;
    unsigned short* kvwb = qwb  + qwN;
    unsigned short* wowb = kvwb + kvwN;
    unsigned short* Q16  = wowb + qwN;
    unsigned short* K16  = Q16  + qN;
    unsigned short* VT16 = K16  + kvN;
    unsigned short* AO16 = VT16 + kvN;
    // RoPE table aliased over AO16: written by prep, read by qkv,
    // dead before attn writes AO16.  2048*48 float2 = 786 KB < |AO16|.
    float2* tab = (float2*)AO16;

    constexpr int PREP_TOT = (MROWS * DIMD + 2 * DIMD * DIMD
                              + 2 * KVHD * HDD * DIMD) / 4 + SEQL * 48;
    prep_kernel<<<(PREP_TOT + 255) / 256, 256, 0, stream>>>(
        (const float4*)x, (const float4*)qw, (const float4*)kvw, (const float4*)wow,
        (ushort4*)xb, (ushort4*)qwb, (ushort4*)kvwb, (ushort4*)wowb, sp, tab);

    qkv_mfma_kernel<<<dim3(NQKV / 64, MROWS / 128, 1), 256, 0, stream>>>(
        xb, qwb, kvwb, qb, kvb, tab, Q16, K16, VT16);
    attn_mfma_kernel<<<dim3((SEQL / 64) * NHD * BSZ4, 1, 1), 256, 0, stream>>>(
        Q16, K16, VT16, AO16);
    out_mfma_kernel<<<dim3(DIMD / 64, MROWS / 128, 1), 256, 0, stream>>>(
        AO16, wowb, wob, (float*)d_out);
}

// Round 11
// 286.125 us; speedup vs baseline: 1.0322x; 1.0322x over previous
//
#include <hip/hip_runtime.h>
#include <hip/hip_bf16.h>

// Problem constants
constexpr int DIMD  = 1152;
constexpr int NHD   = 12;     // query heads
constexpr int KVHD  = 2;      // kv heads
constexpr int HDD   = 96;     // head dim
constexpr int GRPS  = 6;      // GQA group size
constexpr int SEQL  = 2048;
constexpr int BSZ4  = 4;
constexpr int MROWS = BSZ4 * SEQL;           // 8192
constexpr int NQKV  = DIMD + 2 * KVHD * HDD; // 1536
constexpr float SCALE = 0.10206207261596577f; // 96^-0.5
// exp2-domain scale: SCALE * log2(e). v_exp_f32 computes 2^x natively.
constexpr float SCALE2 = 0.10206207261596577f * 1.4426950408889634f;

typedef short  bf16x8 __attribute__((ext_vector_type(8)));
typedef float  f32x4  __attribute__((ext_vector_type(4)));
typedef float  f32x16 __attribute__((ext_vector_type(16)));
typedef unsigned int u32x4_t __attribute__((ext_vector_type(4)));

typedef __attribute__((address_space(3))) unsigned int       lds_u32_t;
typedef __attribute__((address_space(1))) const unsigned int glb_u32_t;

__device__ __forceinline__ void gload16(const unsigned short* g, unsigned short* l) {
    // async global->LDS DMA, 16B/lane; LDS dest = wave-uniform base + lane*16
    __builtin_amdgcn_global_load_lds((glb_u32_t*)(const void*)g,
                                     (lds_u32_t*)(void*)l, 16, 0, 0);
}

__device__ __forceinline__ unsigned short f2bf(float f) {
    unsigned int u = __builtin_bit_cast(unsigned int, f);
    u += 0x7fff + ((u >> 16) & 1);   // RNE
    return (unsigned short)(u >> 16);
}

__device__ __forceinline__ unsigned cvtpk(float a, float b) {
    // packed f32->bf16 (RNE): lo16 = bf16(a), hi16 = bf16(b)
    unsigned r;
    asm volatile("v_cvt_pk_bf16_f32 %0, %1, %2" : "=v"(r) : "v"(a), "v"(b));
    return r;
}

__device__ __forceinline__ float ex2(float x) {
    // raw v_exp_f32: D = 2^S0 (glibc macro-clash-free replacement for __exp2f)
    float r;
    asm volatile("v_exp_f32 %0, %1" : "=v"(r) : "v"(x));
    return r;
}

// ---------------------------------------------------------------------------
// prep: fused fp32->bf16 converts (x, qw, kvw, wow) + RoPE cos/sin table.
// ---------------------------------------------------------------------------
__device__ __forceinline__ void cvt4(const float4* __restrict__ s,
                                     ushort4* __restrict__ d, int i) {
    float4 f = s[i];
    ushort4 o;
    o.x = f2bf(f.x); o.y = f2bf(f.y); o.z = f2bf(f.z); o.w = f2bf(f.w);
    d[i] = o;
}

__global__ __launch_bounds__(256) void prep_kernel(
    const float4* __restrict__ x,   const float4* __restrict__ qw,
    const float4* __restrict__ kvw, const float4* __restrict__ wow,
    ushort4* __restrict__ xb,   ushort4* __restrict__ qwb,
    ushort4* __restrict__ kvwb, ushort4* __restrict__ wowb,
    const int* __restrict__ sp, float2* __restrict__ tab)
{
    constexpr int X4  = MROWS * DIMD / 4;
    constexpr int W4  = DIMD * DIMD / 4;
    constexpr int KV4 = 2 * KVHD * HDD * DIMD / 4;
    constexpr int NT  = SEQL * 48;
    int i = blockIdx.x * 256 + threadIdx.x;
    if (i < X4)  { cvt4(x, xb, i); return; }
    i -= X4;
    if (i < W4)  { cvt4(qw, qwb, i); return; }
    i -= W4;
    if (i < KV4) { cvt4(kvw, kvwb, i); return; }
    i -= KV4;
    if (i < W4)  { cvt4(wow, wowb, i); return; }
    i -= W4;
    if (i < NT) {
        int s = i / 48, j = i - (i / 48) * 48;
        float th = powf(10000.0f, -(float)(2 * j) / 96.0f);
        float ang = (float)(s + *sp) * th;
        float sn, cs; sincosf(ang, &sn, &cs);
        tab[i] = make_float2(cs, sn);
    }
}

// ---------------------------------------------------------------------------
// Kernel 1: QKV projection (128x128 tiles, depth-2 prefetch + XCD swizzle).
// Reverted to the R9-measured config: R10's 128x64 split regressed +11 µs —
// the GEMMs are per-K-step-overhead-bound (2 barriers + wait per step), so
// halving per-wave MFMA work per step amortizes the overhead WORSE.
// ---------------------------------------------------------------------------
__global__ __launch_bounds__(256) void qkv_mfma_kernel(
    const unsigned short* __restrict__ xb,  const unsigned short* __restrict__ qwb,
    const unsigned short* __restrict__ kvwb,
    const float* __restrict__ qb,  const float* __restrict__ kvb,
    const float2* __restrict__ tab,
    unsigned short* __restrict__ Qo, unsigned short* __restrict__ Ko,
    unsigned short* __restrict__ VTo)
{
    __shared__ __align__(16) unsigned short As[3][128 * 32];
    __shared__ __align__(16) unsigned short Bs[3][128 * 32];

    const int tid  = threadIdx.x;
    const int w    = tid >> 6;
    const int lane = tid & 63;
    const int l16  = lane & 15;
    const int quad = lane >> 4;
    const int wm   = w >> 1, wn = w & 1;

    const int flat = (int)(blockIdx.y * gridDim.x + blockIdx.x);  // 0..767
    const int swz  = (flat & 7) * 96 + (flat >> 3);
    const int m0   = (swz / 12) * 128;
    const int n0   = (swz % 12) * 128;

    const unsigned short* Abase = xb + (size_t)m0 * DIMD;
    const unsigned short* Bbase = (n0 < DIMD)
        ? qwb  + (size_t)n0 * DIMD
        : kvwb + (size_t)(n0 - DIMD) * DIMD;

    const int srow = w * 16 + (lane >> 2);
    const int scol = (lane & 3) * 8;

    f32x4 acc[4][4];
    #pragma unroll
    for (int mi = 0; mi < 4; mi++)
        #pragma unroll
        for (int ni = 0; ni < 4; ni++) acc[mi][ni] = (f32x4){0.f, 0.f, 0.f, 0.f};

    constexpr int NK = DIMD / 32;   // 36

    gload16(Abase + (size_t)srow        * DIMD + scol, &As[0][w * 512]);
    gload16(Abase + (size_t)(srow + 64) * DIMD + scol, &As[0][2048 + w * 512]);
    gload16(Bbase + (size_t)srow        * DIMD + scol, &Bs[0][w * 512]);
    gload16(Bbase + (size_t)(srow + 64) * DIMD + scol, &Bs[0][2048 + w * 512]);
    gload16(Abase + (size_t)srow        * DIMD + 32 + scol, &As[1][w * 512]);
    gload16(Abase + (size_t)(srow + 64) * DIMD + 32 + scol, &As[1][2048 + w * 512]);
    gload16(Bbase + (size_t)srow        * DIMD + 32 + scol, &Bs[1][w * 512]);
    gload16(Bbase + (size_t)(srow + 64) * DIMD + 32 + scol, &Bs[1][2048 + w * 512]);

    for (int kt = 0; kt < NK; kt++) {
        const int cur = kt % 3;
        if (kt + 2 < NK) {
            const int stg = (kt + 2) % 3;
            const int k0  = (kt + 2) * 32;
            gload16(Abase + (size_t)srow        * DIMD + k0 + scol, &As[stg][w * 512]);
            gload16(Abase + (size_t)(srow + 64) * DIMD + k0 + scol, &As[stg][2048 + w * 512]);
            gload16(Bbase + (size_t)srow        * DIMD + k0 + scol, &Bs[stg][w * 512]);
            gload16(Bbase + (size_t)(srow + 64) * DIMD + k0 + scol, &Bs[stg][2048 + w * 512]);
            asm volatile("s_waitcnt vmcnt(8)" ::: "memory");
        } else if (kt + 1 < NK) {
            asm volatile("s_waitcnt vmcnt(4)" ::: "memory");
        } else {
            asm volatile("s_waitcnt vmcnt(0)" ::: "memory");
        }
        __builtin_amdgcn_s_barrier();
        asm volatile("" ::: "memory");

        bf16x8 af[4], bfr[4];
        #pragma unroll
        for (int mi = 0; mi < 4; mi++)
            af[mi] = *(const bf16x8*)&As[cur][(wm * 64 + mi * 16 + l16) * 32 + quad * 8];
        #pragma unroll
        for (int ni = 0; ni < 4; ni++)
            bfr[ni] = *(const bf16x8*)&Bs[cur][(wn * 64 + ni * 16 + l16) * 32 + quad * 8];
        #pragma unroll
        for (int mi = 0; mi < 4; mi++)
            #pragma unroll
            for (int ni = 0; ni < 4; ni++)
                acc[mi][ni] = __builtin_amdgcn_mfma_f32_16x16x32_bf16(
                    af[mi], bfr[ni], acc[mi][ni], 0, 0, 0);

        asm volatile("" ::: "memory");
        __builtin_amdgcn_s_barrier();
    }

    #pragma unroll
    for (int ni = 0; ni < 4; ni++) {
        const int n   = n0 + wn * 64 + ni * 16 + l16;
        const bool isQ = (n < DIMD);
        const int jj  = n - DIMD;
        const bool isK = !isQ && (jj < KVHD * HDD);
        const int d   = isQ ? (n % HDD) : (jj % HDD);
        const int hh  = isQ ? (n / HDD) : ((jj / HDD) & 1);
        const float bias = isQ ? qb[n] : kvb[jj];
        const bool doRope = isQ || isK;
        const int de2 = (d >> 1);
        const float sg = (n & 1) ? 1.0f : -1.0f;
        #pragma unroll
        for (int mi = 0; mi < 4; mi++) {
            #pragma unroll
            for (int r = 0; r < 4; r++) {
                const int m = m0 + wm * 64 + mi * 16 + quad * 4 + r;
                const int b = m >> 11;
                const int s = m & (SEQL - 1);
                float v  = acc[mi][ni][r] + bias;
                float pv = __shfl_xor(v, 1, 64);
                float o = v;
                if (doRope) {
                    float2 cs2 = tab[s * 48 + de2];
                    o = v * cs2.x + sg * pv * cs2.y;
                }
                if (isQ)
                    Qo[(((size_t)b * NHD + hh) * SEQL + s) * HDD + d] = f2bf(o);
                else if (isK)
                    Ko[(((size_t)b * KVHD + hh) * SEQL + s) * HDD + d] = f2bf(o);
                else
                    VTo[(((size_t)b * KVHD + hh) * HDD + d) * SEQL + s] = f2bf(o);
            }
        }
    }
}

// ---------------------------------------------------------------------------
// Kernel 2: bf16 MFMA causal flash attention — R9 kernel VERBATIM (measured
// 83.8 µs, zero bank conflicts, FETCH 12.4 MB). Attn is barrier/latency-
// structure-bound; pipe-level fixes are exhausted.
// ---------------------------------------------------------------------------
__global__ __launch_bounds__(256, 3) void attn_mfma_kernel(
    const unsigned short* __restrict__ Q, const unsigned short* __restrict__ K,
    const unsigned short* __restrict__ VT, unsigned short* __restrict__ AO)
{
    constexpr int KHALF = 64 * 104;                      // shorts per K buffer
    __shared__ __align__(16) unsigned short Ks[2 * KHALF]; // 26624 B (dbuf)
    __shared__ __align__(16) unsigned short VTs[96 * 72];  // 13824 B
    __shared__ float Al[4][32];                            // 512 B (tot 40960)

    const int tid  = threadIdx.x;
    const int w    = tid >> 6;
    const int lane = tid & 63;
    const int l31  = lane & 31;
    const int hi   = lane >> 5;
    const int qh   = w >> 1;      // q-half of the 64-row block
    const int th   = w & 1;       // t-half of each 64-t tile
    const int th32 = th * 32;

    // XCD KV-affinity + per-XCD LPT
    const int idx  = (int)blockIdx.x;
    const int grp  = idx & 7;            // -> XCD (round-robin dispatch)
    const int j0   = idx >> 3;           // 0..191, qt-descending
    const int jq   = j0 / 6;
    const int hrem = j0 - jq * 6;
    const int qt   = 31 - jq;
    const int b    = grp >> 1;
    const int kvh  = grp & 1;
    const int h    = kvh * GRPS + hrem;
    const int nkb  = qt + 1;

    const unsigned short* Qbase  = Q  + (((size_t)b * NHD  + h)   * SEQL) * HDD;
    const unsigned short* Kbase  = K  + (((size_t)b * KVHD + kvh) * SEQL) * HDD;
    const unsigned short* VTbase = VT + (((size_t)b * KVHD + kvh) * HDD)  * SEQL;

    // --- staging maps (identical to R6/R8): instr i = w + 4*j
    int goff[7]; int gkind[7]; int loff[7];
    #pragma unroll
    for (int jj = 0; jj < 7; jj++) {
        const int i = w + 4 * jj;
        gkind[jj] = 2; goff[jj] = 0; loff[jj] = 0;
        if (i < 13) {
            int slot = i * 64 + lane;
            int r = slot / 13, g = slot - r * 13;
            goff[jj]  = r * HDD + (g < 12 ? g * 8 : 0);
            gkind[jj] = 0;
            loff[jj]  = i * 512;
        } else if (i < 27) {
            int iv = i - 13;
            int slot = iv * 64 + lane;
            if (slot < 864) {
                int r = slot / 9, g = slot - r * 9;
                goff[jj]  = r * SEQL + (g < 8 ? g * 8 : 0);
                gkind[jj] = 1;
                loff[jj]  = iv * 512;
            }
        }
    }

    // --- Q fragments (B-operand, 32x32x16): lane l31 = q-col, k = hi*8 + j
    const int qv = qt * 64 + qh * 32;    // wave's q base
    bf16x8 qf[6];
    {
        const unsigned short* qp = Qbase + (size_t)(qv + l31) * HDD + hi * 8;
        #pragma unroll
        for (int ks = 0; ks < 6; ks++) qf[ks] = *(const bf16x8*)(qp + ks * 16);
    }

    float m_r = -1e30f, l_r = 0.0f;
    f32x16 oacc[3];
    #pragma unroll
    for (int nn = 0; nn < 3; nn++)
        #pragma unroll
        for (int r = 0; r < 16; r++) oacc[nn][r] = 0.0f;

    // --- prologue: issue K0 -> buf0, then V0 (K before V: wait math relies on it)
    #pragma unroll
    for (int jj = 0; jj < 7; jj++)
        if (gkind[jj] == 0)
            gload16(Kbase + goff[jj], &Ks[loff[jj]]);
    #pragma unroll
    for (int jj = 0; jj < 7; jj++)
        if (gkind[jj] == 1) {
            if ((w + 4 * jj) < 26 || lane < 32)
                gload16(VTbase + goff[jj], &VTs[loff[jj]]);
        }

    for (int kb = 0; kb < nkb; kb++) {
        const int  cur  = kb & 1;
        const bool more = (kb + 1 < nkb);
        const int  k0   = kb * 64;
        const bool active = (k0 + th32 <= qv + 31);   // wave-uniform

        // ---- issue K(kb+1) into the other buffer, then wait for K(kb) only.
        if (more) {
            const size_t kg = (size_t)(kb + 1) * 64 * HDD;
            #pragma unroll
            for (int jj = 0; jj < 7; jj++)
                if (gkind[jj] == 0)
                    gload16(Kbase + kg + goff[jj], &Ks[(cur ^ 1) * KHALF + loff[jj]]);
            asm volatile("s_waitcnt vmcnt(6)" ::: "memory");
        } else {
            asm volatile("s_waitcnt vmcnt(3)" ::: "memory");
        }
        __builtin_amdgcn_s_barrier();
        asm volatile("" ::: "memory");

        bf16x8 pa[2];
        bool resc = false;

        if (active) {
            // ---- S^T = K[t-half] * Q^T : C col l31 = q, row regs = t_local
            const unsigned short* ksb = &Ks[cur * KHALF + th32 * 104];
            f32x16 s;
            #pragma unroll
            for (int r = 0; r < 16; r++) s[r] = 0.0f;
            __builtin_amdgcn_s_setprio(1);
            #pragma unroll
            for (int ks = 0; ks < 6; ks++) {
                bf16x8 kf = *(const bf16x8*)&ksb[l31 * 104 + ks * 16 + hi * 8];
                s = __builtin_amdgcn_mfma_f32_32x32x16_bf16(kf, qf[ks], s, 0, 0, 0);
            }
            __builtin_amdgcn_s_setprio(0);

            // ---- online softmax (exp2 domain); lane q = qv + l31
            const int qabs = qv + l31;
            float p[16];
            float mx = -3e30f;
            const bool domask = (k0 + th32 + 31 > qv);
            #pragma unroll
            for (int r = 0; r < 16; r++) {
                const int tl = (r & 3) + 8 * (r >> 2) + 4 * hi;
                float x = s[r] * SCALE2;
                if (domask && (k0 + th32 + tl > qabs)) x = -1e30f;
                p[r] = x;
                mx = fmaxf(mx, x);
            }
            mx = fmaxf(mx, __shfl_xor(mx, 32, 64));

            // defer-max: skip rescale when max didn't grow past THR=8
            resc = !__all(mx <= m_r + 8.0f);
            float mnew = m_r, al = 1.0f;
            if (resc) {
                mnew = fmaxf(m_r, mx);
                al = ex2(m_r - mnew);
                if (hi == 0) Al[w][l31] = al;
            }
            float sum = 0.0f;
            #pragma unroll
            for (int r = 0; r < 16; r++) {
                p[r] = ex2(p[r] - mnew);
                sum += p[r];
            }
            sum += __shfl_xor(sum, 32, 64);
            l_r = l_r * al + sum;
            m_r = mnew;

            // ---- P -> two bf16 A-frags in-register (one u32-pair swap per tk)
            #pragma unroll
            for (int tk = 0; tk < 2; tk++) {
                const int base = tk * 8;
                unsigned pkA0 = cvtpk(p[base + 0], p[base + 1]);
                unsigned pkA1 = cvtpk(p[base + 2], p[base + 3]);
                unsigned pkB0 = cvtpk(p[base + 4], p[base + 5]);
                unsigned pkB1 = cvtpk(p[base + 6], p[base + 7]);
                unsigned S0 = hi ? pkA0 : pkB0;
                unsigned S1 = hi ? pkA1 : pkB1;
                unsigned R0 = __shfl_xor(S0, 32, 64);
                unsigned R1 = __shfl_xor(S1, 32, 64);
                u32x4_t wv;
                wv[0] = hi ? R0 : pkA0;
                wv[1] = hi ? R1 : pkA1;
                wv[2] = hi ? pkB0 : R0;
                wv[3] = hi ? pkB1 : R1;
                pa[tk] = __builtin_bit_cast(bf16x8, wv);
            }
        }

        // ---- wait for V(kb): outstanding = V(kb), K(kb+1); min K' = 3
        if (more) asm volatile("s_waitcnt vmcnt(3)" ::: "memory");
        else      asm volatile("s_waitcnt vmcnt(0)" ::: "memory");
        __builtin_amdgcn_s_barrier();
        asm volatile("" ::: "memory");

        if (active) {
            // ---- rescale O only when max moved (wave-uniform branch)
            if (resc) {
                const float4 a0 = *(const float4*)&Al[w][hi * 4];
                const float4 a1 = *(const float4*)&Al[w][8 + hi * 4];
                const float4 a2 = *(const float4*)&Al[w][16 + hi * 4];
                const float4 a3 = *(const float4*)&Al[w][24 + hi * 4];
                const float ab[16] = {a0.x, a0.y, a0.z, a0.w,
                                      a1.x, a1.y, a1.z, a1.w,
                                      a2.x, a2.y, a2.z, a2.w,
                                      a3.x, a3.y, a3.z, a3.w};
                #pragma unroll
                for (int nn = 0; nn < 3; nn++)
                    #pragma unroll
                    for (int r = 0; r < 16; r++) oacc[nn][r] *= ab[r];
            }

            // ---- O += P V[t-half]  (C: col l31 = d, row regs = q_local)
            __builtin_amdgcn_s_setprio(1);
            #pragma unroll
            for (int nn = 0; nn < 3; nn++) {
                const unsigned short* vr = &VTs[(nn * 32 + l31) * 72 + th32 + hi * 8];
                bf16x8 vb0 = *(const bf16x8*)(vr);
                bf16x8 vb1 = *(const bf16x8*)(vr + 16);
                f32x16 a = oacc[nn];
                a = __builtin_amdgcn_mfma_f32_32x32x16_bf16(pa[0], vb0, a, 0, 0, 0);
                a = __builtin_amdgcn_mfma_f32_32x32x16_bf16(pa[1], vb1, a, 0, 0, 0);
                oacc[nn] = a;
            }
            __builtin_amdgcn_s_setprio(0);
        }

        // ---- all waves done reading VTs -> safe to overwrite with V(kb+1)
        asm volatile("" ::: "memory");
        __builtin_amdgcn_s_barrier();
        asm volatile("" ::: "memory");

        if (more) {
            const int kg = (kb + 1) * 64;
            #pragma unroll
            for (int jj = 0; jj < 7; jj++)
                if (gkind[jj] == 1) {
                    if ((w + 4 * jj) < 26 || lane < 32)
                        gload16(VTbase + kg + goff[jj], &VTs[loff[jj]]);
                }
        }
    }

    // ---- epilogue: merge the two t-half states per q-pair, normalize, store.
    __syncthreads();
    float* Mx  = (float*)VTs;          // [4][32] running max
    float* Lx  = Mx + 128;             // [4][32] running sum
    float* Gs  = Lx + 128;             // [4][32] merge factor
    float* Osc = (float*)Ks;           // [2][32][96] partner O dump
    if (hi == 0) { Mx[w * 32 + l31] = m_r; Lx[w * 32 + l31] = l_r; }
    __syncthreads();
    {
        const int wp = w ^ 1;          // t-half partner (same q-half)
        const float m_p = Mx[wp * 32 + l31];
        const float l_p = Lx[wp * 32 + l31];
        const float mm  = fmaxf(m_r, m_p);
        const float fs  = ex2(m_r - mm);
        const float lt  = l_r * fs + l_p * ex2(m_p - mm);
        if (hi == 0) Gs[w * 32 + l31] = fs / lt;   // folds 1/l normalization
    }
    __syncthreads();
    float gr[16];
    {
        const float4 a0 = *(const float4*)&Gs[w * 32 + hi * 4];
        const float4 a1 = *(const float4*)&Gs[w * 32 + 8 + hi * 4];
        const float4 a2 = *(const float4*)&Gs[w * 32 + 16 + hi * 4];
        const float4 a3 = *(const float4*)&Gs[w * 32 + 24 + hi * 4];
        gr[0]  = a0.x; gr[1]  = a0.y; gr[2]  = a0.z; gr[3]  = a0.w;
        gr[4]  = a1.x; gr[5]  = a1.y; gr[6]  = a1.z; gr[7]  = a1.w;
        gr[8]  = a2.x; gr[9]  = a2.y; gr[10] = a2.z; gr[11] = a2.w;
        gr[12] = a3.x; gr[13] = a3.y; gr[14] = a3.z; gr[15] = a3.w;
    }
    #pragma unroll
    for (int nn = 0; nn < 3; nn++)
        #pragma unroll
        for (int r = 0; r < 16; r++) oacc[nn][r] *= gr[r];

    if (th == 1) {
        #pragma unroll
        for (int nn = 0; nn < 3; nn++)
            #pragma unroll
            for (int r = 0; r < 16; r++) {
                const int ql = (r & 3) + 8 * (r >> 2) + 4 * hi;
                Osc[(qh * 32 + ql) * 96 + nn * 32 + l31] = oacc[nn][r];
            }
    }
    __syncthreads();
    if (th == 0) {
        #pragma unroll
        for (int nn = 0; nn < 3; nn++)
            #pragma unroll
            for (int r = 0; r < 16; r++) {
                const int ql = (r & 3) + 8 * (r >> 2) + 4 * hi;
                const float v2 = oacc[nn][r]
                               + Osc[(qh * 32 + ql) * 96 + nn * 32 + l31];
                AO[((size_t)b * SEQL + qv + ql) * DIMD + h * HDD + nn * 32 + l31]
                    = f2bf(v2);
            }
    }
}

// ---------------------------------------------------------------------------
// Kernel 3: output projection (128x128 tiles, depth-2 + XCD swizzle) —
// reverted to R9-measured config.
// ---------------------------------------------------------------------------
__global__ __launch_bounds__(256) void out_mfma_kernel(
    const unsigned short* __restrict__ Ab, const unsigned short* __restrict__ Wb,
    const float* __restrict__ wob, float* __restrict__ out)
{
    __shared__ __align__(16) unsigned short As[3][128 * 32];
    __shared__ __align__(16) unsigned short Bs[3][128 * 32];

    const int tid  = threadIdx.x;
    const int w    = tid >> 6;
    const int lane = tid & 63;
    const int l16  = lane & 15;
    const int quad = lane >> 4;
    const int wm   = w >> 1, wn = w & 1;

    const int flat = (int)(blockIdx.y * gridDim.x + blockIdx.x);  // 0..575
    const int swz  = (flat & 7) * 72 + (flat >> 3);
    const int m0   = (swz / 9) * 128;
    const int n0   = (swz % 9) * 128;

    const unsigned short* Abase = Ab + (size_t)m0 * DIMD;
    const unsigned short* Bbase = Wb + (size_t)n0 * DIMD;

    const int srow = w * 16 + (lane >> 2);
    const int scol = (lane & 3) * 8;

    f32x4 acc[4][4];
    #pragma unroll
    for (int mi = 0; mi < 4; mi++)
        #pragma unroll
        for (int ni = 0; ni < 4; ni++) acc[mi][ni] = (f32x4){0.f, 0.f, 0.f, 0.f};

    constexpr int NK = DIMD / 32;   // 36

    gload16(Abase + (size_t)srow        * DIMD + scol, &As[0][w * 512]);
    gload16(Abase + (size_t)(srow + 64) * DIMD + scol, &As[0][2048 + w * 512]);
    gload16(Bbase + (size_t)srow        * DIMD + scol, &Bs[0][w * 512]);
    gload16(Bbase + (size_t)(srow + 64) * DIMD + scol, &Bs[0][2048 + w * 512]);
    gload16(Abase + (size_t)srow        * DIMD + 32 + scol, &As[1][w * 512]);
    gload16(Abase + (size_t)(srow + 64) * DIMD + 32 + scol, &As[1][2048 + w * 512]);
    gload16(Bbase + (size_t)srow        * DIMD + 32 + scol, &Bs[1][w * 512]);
    gload16(Bbase + (size_t)(srow + 64) * DIMD + 32 + scol, &Bs[1][2048 + w * 512]);

    for (int kt = 0; kt < NK; kt++) {
        const int cur = kt % 3;
        if (kt + 2 < NK) {
            const int stg = (kt + 2) % 3;
            const int k0  = (kt + 2) * 32;
            gload16(Abase + (size_t)srow        * DIMD + k0 + scol, &As[stg][w * 512]);
            gload16(Abase + (size_t)(srow + 64) * DIMD + k0 + scol, &As[stg][2048 + w * 512]);
            gload16(Bbase + (size_t)srow        * DIMD + k0 + scol, &Bs[stg][w * 512]);
            gload16(Bbase + (size_t)(srow + 64) * DIMD + k0 + scol, &Bs[stg][2048 + w * 512]);
            asm volatile("s_waitcnt vmcnt(8)" ::: "memory");
        } else if (kt + 1 < NK) {
            asm volatile("s_waitcnt vmcnt(4)" ::: "memory");
        } else {
            asm volatile("s_waitcnt vmcnt(0)" ::: "memory");
        }
        __builtin_amdgcn_s_barrier();
        asm volatile("" ::: "memory");

        bf16x8 af[4], bfr[4];
        #pragma unroll
        for (int mi = 0; mi < 4; mi++)
            af[mi] = *(const bf16x8*)&As[cur][(wm * 64 + mi * 16 + l16) * 32 + quad * 8];
        #pragma unroll
        for (int ni = 0; ni < 4; ni++)
            bfr[ni] = *(const bf16x8*)&Bs[cur][(wn * 64 + ni * 16 + l16) * 32 + quad * 8];
        #pragma unroll
        for (int mi = 0; mi < 4; mi++)
            #pragma unroll
            for (int ni = 0; ni < 4; ni++)
                acc[mi][ni] = __builtin_amdgcn_mfma_f32_16x16x32_bf16(
                    af[mi], bfr[ni], acc[mi][ni], 0, 0, 0);

        asm volatile("" ::: "memory");
        __builtin_amdgcn_s_barrier();
    }

    #pragma unroll
    for (int ni = 0; ni < 4; ni++) {
        const int n = n0 + wn * 64 + ni * 16 + l16;
        const float bias = wob[n];
        #pragma unroll
        for (int mi = 0; mi < 4; mi++) {
            #pragma unroll
            for (int r = 0; r < 4; r++) {
                const int m = m0 + wm * 64 + mi * 16 + quad * 4 + r;
                out[(size_t)m * DIMD + n] = acc[mi][ni][r] + bias;
            }
        }
    }
}

// ---------------------------------------------------------------------------
extern "C" void kernel_launch(void* const* d_in, const int* in_sizes, int n_in,
                              void* d_out, int out_size, void* d_ws, size_t ws_size,
                              hipStream_t stream)
{
    const float* x   = (const float*)d_in[0];
    // d_in[1] = mask: exactly triu(-1e9, k=1) -> causal predicate in-kernel
    const float* qw  = (const float*)d_in[2];
    const float* qb  = (const float*)d_in[3];
    const float* kvw = (const float*)d_in[4];
    const float* kvb = (const float*)d_in[5];
    const float* wow = (const float*)d_in[6];
    const float* wob = (const float*)d_in[7];
    const int*   sp  = (const int*)d_in[8];

    const size_t xN   = (size_t)MROWS * DIMD;
    const size_t qwN  = (size_t)DIMD * DIMD;
    const size_t kvwN = (size_t)2 * KVHD * HDD * DIMD;
    const size_t qN   = (size_t)BSZ4 * NHD  * SEQL * HDD;
    const size_t kvN  = (size_t)BSZ4 * KVHD * SEQL * HDD;

    unsigned short* xb   = (unsigned short*)d_ws;
    unsigned short* qwb  = xb   + xN;
    unsigned short* kvwb = qwb  + qwN;
    unsigned short* wowb = kvwb + kvwN;
    unsigned short* Q16  = wowb + qwN;
    unsigned short* K16  = Q16  + qN;
    unsigned short* VT16 = K16  + kvN;
    unsigned short* AO16 = VT16 + kvN;
    // RoPE table aliased over AO16: written by prep, read by qkv,
    // dead before attn writes AO16.  2048*48 float2 = 786 KB < |AO16|.
    float2* tab = (float2*)AO16;

    constexpr int PREP_TOT = (MROWS * DIMD + 2 * DIMD * DIMD
                              + 2 * KVHD * HDD * DIMD) / 4 + SEQL * 48;
    prep_kernel<<<(PREP_TOT + 255) / 256, 256, 0, stream>>>(
        (const float4*)x, (const float4*)qw, (const float4*)kvw, (const float4*)wow,
        (ushort4*)xb, (ushort4*)qwb, (ushort4*)kvwb, (ushort4*)wowb, sp, tab);

    qkv_mfma_kernel<<<dim3(NQKV / 128, MROWS / 128, 1), 256, 0, stream>>>(
        xb, qwb, kvwb, qb, kvb, tab, Q16, K16, VT16);
    attn_mfma_kernel<<<dim3((SEQL / 64) * NHD * BSZ4, 1, 1), 256, 0, stream>>>(
        Q16, K16, VT16, AO16);
    out_mfma_kernel<<<dim3(DIMD / 128, MROWS / 128, 1), 256, 0, stream>>>(
        AO16, wowb, wob, (float*)d_out);
}